// Round 6
// baseline (17688.713 us; speedup 1.0000x reference)
//
#include <hip/hip_runtime.h>
#include <hip/hip_bf16.h>

#define SS 128
#define TT 128
#define NBLK 256
#define FSTRIDE 16   // one flag per 64B cacheline

__device__ __forceinline__ float sigf(float x) { return 1.f / (1.f + __expf(-x)); }

// Write-through coherent store (to MALL): producers of cross-block data.
__device__ __forceinline__ void cstore(float* p, float v) {
  __hip_atomic_store(p, v, __ATOMIC_RELAXED, __HIP_MEMORY_SCOPE_AGENT);
}

// ---------------------------------------------------------------------------
// Device-wide barrier, flag-array, no acquire-invalidate.
// Consumers read ring buffers via PLAIN CACHED loads: safe because every ring
// address is written exactly once per dispatch (write-through to MALL) before
// any read, and was never cached earlier in the dispatch (entry acquire
// invalidated L1/L2) -> first read fills L2 with fresh data, rest of XCD hits.
__device__ __forceinline__ void gbar(unsigned* flags, unsigned gen) {
  __syncthreads();
  unsigned* go = flags + NBLK * FSTRIDE;
  int tid = threadIdx.x;
  if (blockIdx.x == 0) {
    if (tid > 0) {
      int guard = 0;
      while (__hip_atomic_load(&flags[tid * FSTRIDE], __ATOMIC_RELAXED,
                               __HIP_MEMORY_SCOPE_AGENT) < gen &&
             ++guard < (1 << 20))
        __builtin_amdgcn_s_sleep(1);
    }
    __syncthreads();
    if (tid == 0)
      __hip_atomic_store(go, gen, __ATOMIC_RELEASE, __HIP_MEMORY_SCOPE_AGENT);
  } else {
    if (tid == 0) {
      __hip_atomic_store(&flags[blockIdx.x * FSTRIDE], gen, __ATOMIC_RELEASE,
                         __HIP_MEMORY_SCOPE_AGENT);
      int guard = 0;
      while (__hip_atomic_load(go, __ATOMIC_RELAXED,
                               __HIP_MEMORY_SCOPE_AGENT) < gen &&
             ++guard < (1 << 20))
        __builtin_amdgcn_s_sleep(1);
    }
    __syncthreads();
  }
  asm volatile("" ::: "memory");
}

// ---------------------------------------------------------------------------
// Gate partials over this wave's k-quarter. x via PLAIN cached loads
// ([k][64b] layout, lane=batch, coalesced 256B/row); weights from LDS
// (wave-uniform broadcast). unroll 16 keeps 64 x-loads in flight.
template<int NJ, int NK4, int LDW>
__device__ __forceinline__ void mac_lds(const float* __restrict__ xg,
                                        const float* __restrict__ wl,
                                        float* __restrict__ acc) {
#pragma unroll 16
  for (int k4 = 0; k4 < NK4; ++k4) {
    float x0 = xg[(k4 * 4 + 0) * 64];
    float x1 = xg[(k4 * 4 + 1) * 64];
    float x2 = xg[(k4 * 4 + 2) * 64];
    float x3 = xg[(k4 * 4 + 3) * 64];
#pragma unroll
    for (int j = 0; j < NJ; ++j) {
      const float4 w4 = *(const float4*)(wl + j * LDW + k4 * 4);
      acc[j] += x0 * w4.x + x1 * w4.y + x2 * w4.z + x3 * w4.w;
    }
  }
}

// ---------------------------------------------------------------------------
__global__ void k_embed(const float* __restrict__ emb, const int* __restrict__ toks,
                        float* __restrict__ out, int seqlen) {
  int s = blockIdx.x >> 6, b = blockIdx.x & 63;
  int tok = toks[b * seqlen + s];
  const float4* src = (const float4*)(emb + (size_t)tok * 512);
  float4* dst = (float4*)(out + (size_t)blockIdx.x * 512);
  dst[threadIdx.x] = src[threadIdx.x];
}

// ---------------------------------------------------------------------------
// GEMM C[m][n] = X[m]·W[n] + b1[n] + b2[n].
// MODE 1: write GT[((m>>6)*ldc + n)*64 + (m&63)]   (per-timestep transposed gates)
// MODE 2: write out[((m&63)*512 + n)*128 + (m>>6)] (final [B][OUT][T])
template<int MODE>
__global__ __launch_bounds__(256) void k_gemm(
    const float* __restrict__ X, int ldx,
    const float* __restrict__ W, int ldw, int koff,
    const float* __restrict__ b1, const float* __restrict__ b2,
    float* __restrict__ C, int ldc, int K) {
  __shared__ float Xs[16][132];
  __shared__ float Ws[16][132];
  int m0 = blockIdx.y * 128, n0 = blockIdx.x * 128;
  int tx = threadIdx.x & 15, ty = threadIdx.x >> 4;
  float acc[8][8] = {};
  for (int k0 = 0; k0 < K; k0 += 16) {
    __syncthreads();
#pragma unroll
    for (int j = 0; j < 2; ++j) {
      int f4 = threadIdx.x + j * 256;
      int row = f4 >> 2, kc = (f4 & 3) * 4;
      float4 xv = *(const float4*)&X[(size_t)(m0 + row) * ldx + k0 + kc];
      Xs[kc + 0][row] = xv.x; Xs[kc + 1][row] = xv.y;
      Xs[kc + 2][row] = xv.z; Xs[kc + 3][row] = xv.w;
      float4 wv = *(const float4*)&W[(size_t)(n0 + row) * ldw + koff + k0 + kc];
      Ws[kc + 0][row] = wv.x; Ws[kc + 1][row] = wv.y;
      Ws[kc + 2][row] = wv.z; Ws[kc + 3][row] = wv.w;
    }
    __syncthreads();
#pragma unroll
    for (int kk = 0; kk < 16; ++kk) {
      float a[8], w[8];
      *(float4*)&a[0] = *(const float4*)&Xs[kk][ty * 8];
      *(float4*)&a[4] = *(const float4*)&Xs[kk][ty * 8 + 4];
      *(float4*)&w[0] = *(const float4*)&Ws[kk][tx * 8];
      *(float4*)&w[4] = *(const float4*)&Ws[kk][tx * 8 + 4];
#pragma unroll
      for (int i = 0; i < 8; ++i)
#pragma unroll
        for (int j = 0; j < 8; ++j)
          acc[i][j] += a[i] * w[j];
    }
  }
  float bias[8];
#pragma unroll
  for (int j = 0; j < 8; ++j) {
    int n = n0 + tx * 8 + j;
    bias[j] = (b1 ? b1[n] : 0.f) + (b2 ? b2[n] : 0.f);
  }
  for (int i = 0; i < 8; ++i) {
    int m = m0 + ty * 8 + i;
#pragma unroll
    for (int j = 0; j < 8; ++j) {
      int n = n0 + tx * 8 + j;
      float v = acc[i][j] + bias[j];
      if (MODE == 1)
        C[((size_t)(m >> 6) * ldc + n) * 64 + (m & 63)] = v;
      else
        C[((size_t)(m & 63) * 512 + n) * 128 + (m >> 6)] = v;
    }
  }
}

// ---------------------------------------------------------------------------
// Persistent encoder layer. Block nb: dir d=nb>>7, gate rows {nbL+128j}.
// Weight slice in LDS. h state in ring rEnc[t][2 dir][256][64] (slot t read at
// step t, slot t+1 written): cached reads, write-through stores.
template<int LOUT>
__global__ __launch_bounds__(256, 1) void enc_persist(
    const float* __restrict__ GT,     // [128][2048][64] input gates
    const float* __restrict__ whh,    // [2][1024][256] this layer
    float* __restrict__ rEnc,         // [129][2][256][64] ring
    float* __restrict__ lout,
    float* __restrict__ hFin,         // [512][64] (decoder h init, dir-concat)
    float* __restrict__ cFin,         // [512][64]
    unsigned* bar) {
  int nb = blockIdx.x;
  int d = nb >> 7, nbL = nb & 127;
  int tid = threadIdx.x;
  int lane = tid & 63;
  int wv = __builtin_amdgcn_readfirstlane(tid >> 6);
  __shared__ float wE[8][256];          // 8 KB weight slice
  __shared__ float pt[4][8][64];
  for (int idx = tid; idx < 512; idx += 256) {
    int j = idx >> 6, q = idx & 63;
    int row = d * 1024 + nbL + 128 * j;
    *(float4*)&wE[j][q * 4] = *(const float4*)&whh[(size_t)row * 256 + q * 4];
  }
  __syncthreads();

  float creg = 0.f;
  int b = tid & 63, hi = tid >> 6;
  int hu = nbL + hi * 128;

  for (int t = 0; t < SS; ++t) {
    int s = d ? (SS - 1 - t) : t;
    float gi[4];
    if (tid < 128) {
#pragma unroll
      for (int g = 0; g < 4; ++g)
        gi[g] = GT[((size_t)s * 2048 + d * 1024 + g * 256 + hu) * 64 + b];
    }
    if (t > 0) {
      const float* xg = rEnc + (size_t)t * 32768 + d * 16384 + wv * 4096 + lane;
      float acc[8] = {};
      mac_lds<8, 16, 256>(xg, &wE[0][wv * 64], acc);
#pragma unroll
      for (int j = 0; j < 8; ++j) pt[wv][j][lane] = acc[j];
    }
    __syncthreads();
    if (tid < 128) {
      float g4[4];
#pragma unroll
      for (int g = 0; g < 4; ++g) {
        float sum = gi[g];
        if (t > 0)
          sum += pt[0][2 * g + hi][b] + pt[1][2 * g + hi][b] +
                 pt[2][2 * g + hi][b] + pt[3][2 * g + hi][b];
        g4[g] = sum;
      }
      float ig = sigf(g4[0]), fg = sigf(g4[1]), gg = tanhf(g4[2]), og = sigf(g4[3]);
      creg = fg * creg + ig * gg;
      float hn = og * tanhf(creg);
      cstore(&rEnc[(size_t)(t + 1) * 32768 + d * 16384 + hu * 64 + b], hn);
      if (LOUT == 0)
        lout[((size_t)s * 64 + b) * 512 + d * 256 + hu] = hn;
      else
        lout[(size_t)b * 65536 + (size_t)s * 512 + d * 256 + hu] = hn;
      if (t == SS - 1) {
        cstore(&hFin[(d * 256 + hu) * 64 + b], hn);
        cFin[(d * 256 + hu) * 64 + b] = creg;
      }
    }
    if (t < SS - 1) gbar(bar, (unsigned)(t + 1));
  }
}

// ---------------------------------------------------------------------------
// Persistent decoder: 128 steps x 4 phases. Weights (72 KB) in LDS.
// State rings (slot t+1 written at step t; slot 0 = init):
//   rFeed[129][512][64], rH0[129][512][64], rH1[129][512][64], rCtx[128][512][64]
__global__ __launch_bounds__(256, 1) void dec_persist(
    const float* __restrict__ GdT,    // [128][2048][64] emb gates (+biases)
    const float* __restrict__ w_ih0,  // [2048][1024]
    const float* __restrict__ w_hh0,  // [2048][512]
    const float* __restrict__ w_ih1,  // [2048][512]
    const float* __restrict__ w_hh1,  // [2048][512]
    const float* __restrict__ b_ih1, const float* __restrict__ b_hh1,
    const float* __restrict__ attn_w, // [512][1024]
    const float* __restrict__ enc_out,// [64][128][512] batch-major
    const int* __restrict__ src_tokens,
    const float* __restrict__ c0T, const float* __restrict__ c1T,  // [512][64]
    float* __restrict__ rFeed, float* __restrict__ rH0,
    float* __restrict__ rH1, float* __restrict__ rCtx,
    float* __restrict__ houts,        // [8192][512] row-major
    unsigned* bar) {
  int nb = blockIdx.x;
  int tid = threadIdx.x;
  int lane = tid & 63;
  int wv = __builtin_amdgcn_readfirstlane(tid >> 6);
  __shared__ float wA[8][1024];       // 32 KB
  __shared__ float wB[8][1024];       // 32 KB
  __shared__ float wD[2][1024];       // 8 KB
  __shared__ float pt[4][8][64];
  __shared__ float h1s[512];
  __shared__ float sc[128];

  // ---- stage weights into LDS (once) ----
  for (int idx = tid; idx < 2048; idx += 256) {
    int j = idx >> 8, q = idx & 255;
    int k = q * 4, row = nb + 256 * j;
    float4 v = (k < 512)
        ? *(const float4*)&w_ih0[(size_t)row * 1024 + 512 + k]
        : *(const float4*)&w_hh0[(size_t)row * 512 + (k - 512)];
    *(float4*)&wA[j][k] = v;
  }
  for (int idx = tid; idx < 2048; idx += 256) {
    int j = idx >> 8, q = idx & 255;
    int k = q * 4, row = nb + 256 * j;
    float4 v = (k < 512)
        ? *(const float4*)&w_ih1[(size_t)row * 512 + k]
        : *(const float4*)&w_hh1[(size_t)row * 512 + (k - 512)];
    *(float4*)&wB[j][k] = v;
  }
  for (int idx = tid; idx < 512; idx += 256) {
    int j = idx >> 8, q = idx & 255;
    *(float4*)&wD[j][q * 4] =
        *(const float4*)&attn_w[(size_t)(nb * 2 + j) * 1024 + q * 4];
  }
  __syncthreads();

  int bb = tid & 63, hi = tid >> 6;
  int hu = nb + (hi & 1) * 256;
  float c0r = 0.f, c1r = 0.f;
  if (tid < 128) { c0r = c0T[hu * 64 + bb]; c1r = c1T[hu * 64 + bb]; }

  for (int t = 0; t < TT; ++t) {
    unsigned gb = (unsigned)(t * 4);
    size_t cur = (size_t)t * 32768, nxt = (size_t)(t + 1) * 32768;
    // ---- A: cell0 gates (x = [feed | h0] from slot t) ----
    float giA[4];
    if (tid < 128) {
#pragma unroll
      for (int g = 0; g < 4; ++g)
        giA[g] = GdT[((size_t)t * 2048 + g * 512 + hu) * 64 + bb];
    }
    {
      const float* xg = (wv < 2) ? rFeed + cur + wv * 16384 + lane
                                 : rH0 + cur + (wv - 2) * 16384 + lane;
      float acc[8] = {};
      mac_lds<8, 64, 1024>(xg, &wA[0][wv * 256], acc);
#pragma unroll
      for (int j = 0; j < 8; ++j) pt[wv][j][lane] = acc[j];
    }
    __syncthreads();
    if (tid < 128) {
      float g4[4];
#pragma unroll
      for (int g = 0; g < 4; ++g)
        g4[g] = pt[0][2 * g + hi][bb] + pt[1][2 * g + hi][bb] +
                pt[2][2 * g + hi][bb] + pt[3][2 * g + hi][bb] + giA[g];
      float ig = sigf(g4[0]), fg = sigf(g4[1]), gg = tanhf(g4[2]), og = sigf(g4[3]);
      c0r = fg * c0r + ig * gg;
      float hn = og * tanhf(c0r);
      cstore(&rH0[nxt + hu * 64 + bb], hn);
    }
    gbar(bar, gb + 1);
    // ---- B: cell1 gates (x = [h0 slot t+1 | h1 slot t]) ----
    {
      const float* xg = (wv < 2) ? rH0 + nxt + wv * 16384 + lane
                                 : rH1 + cur + (wv - 2) * 16384 + lane;
      float acc[8] = {};
      mac_lds<8, 64, 1024>(xg, &wB[0][wv * 256], acc);
#pragma unroll
      for (int j = 0; j < 8; ++j) pt[wv][j][lane] = acc[j];
    }
    __syncthreads();
    if (tid < 128) {
      float g4[4];
#pragma unroll
      for (int g = 0; g < 4; ++g)
        g4[g] = pt[0][2 * g + hi][bb] + pt[1][2 * g + hi][bb] +
                pt[2][2 * g + hi][bb] + pt[3][2 * g + hi][bb] +
                b_ih1[g * 512 + hu] + b_hh1[g * 512 + hu];
      float ig = sigf(g4[0]), fg = sigf(g4[1]), gg = tanhf(g4[2]), og = sigf(g4[3]);
      c1r = fg * c1r + ig * gg;
      float hn = og * tanhf(c1r);
      cstore(&rH1[nxt + hu * 64 + bb], hn);
    }
    gbar(bar, gb + 2);
    // ---- C: attention (blocks 0..63, one per batch; enc_out [b][s][h]) ----
    if (nb < 64) {
      const float* h1c = rH1 + nxt;
      const float* eb = enc_out + (size_t)nb * 65536;
      for (int i = tid; i < 512; i += 256)
        h1s[i] = h1c[i * 64 + nb];
      __syncthreads();
      {
        int s2 = tid >> 1, half = tid & 1;
        const float* er = eb + (size_t)s2 * 512 + half * 256;
        const float* hh = h1s + half * 256;
        float a = 0.f;
#pragma unroll 8
        for (int k = 0; k < 256; k += 4) {
          float4 ev = *(const float4*)&er[k];
          a += ev.x * hh[k] + ev.y * hh[k + 1] + ev.z * hh[k + 2] + ev.w * hh[k + 3];
        }
        a += __shfl_xor(a, 1);
        if (!half) sc[s2] = (src_tokens[nb * SS + s2] == 0) ? -1e30f : a;
      }
      __syncthreads();
      if (tid < 64) {
        float m = fmaxf(sc[tid], sc[tid + 64]);
        for (int off = 32; off; off >>= 1) m = fmaxf(m, __shfl_xor(m, off));
        float e0 = __expf(sc[tid] - m), e1 = __expf(sc[tid + 64] - m);
        float ssum = e0 + e1;
        for (int off = 32; off; off >>= 1) ssum += __shfl_xor(ssum, off);
        float inv = 1.f / ssum;
        sc[tid] = e0 * inv; sc[tid + 64] = e1 * inv;
      }
      __syncthreads();
      float a0 = 0.f, a1 = 0.f;
      for (int s2 = 0; s2 < 128; ++s2) {
        float p_ = sc[s2];
        const float* er = eb + (size_t)s2 * 512;
        a0 += p_ * er[tid];
        a1 += p_ * er[tid + 256];
      }
      cstore(&rCtx[cur + tid * 64 + nb], a0);
      cstore(&rCtx[cur + (tid + 256) * 64 + nb], a1);
    }
    gbar(bar, gb + 3);
    // ---- D: outproj tanh([ctx slot t | h1 slot t+1]@attn_w^T) ----
    {
      const float* xg = (wv < 2) ? rCtx + cur + wv * 16384 + lane
                                 : rH1 + nxt + (wv - 2) * 16384 + lane;
      float acc[2] = {};
      mac_lds<2, 64, 1024>(xg, &wD[0][wv * 256], acc);
      pt[wv][0][lane] = acc[0];
      pt[wv][1][lane] = acc[1];
    }
    __syncthreads();
    if (tid < 128) {
      int o = nb * 2 + hi;
      float v = tanhf(pt[0][hi][bb] + pt[1][hi][bb] + pt[2][hi][bb] + pt[3][hi][bb]);
      cstore(&rFeed[nxt + o * 64 + bb], v);
      houts[((size_t)t * 64 + bb) * 512 + o] = v;
    }
    if (t < TT - 1) gbar(bar, gb + 4);
  }
}

// ---------------------------------------------------------------------------
extern "C" void kernel_launch(void* const* d_in, const int* in_sizes, int n_in,
                              void* d_out, int out_size, void* d_ws, size_t ws_size,
                              hipStream_t stream) {
  const int*   src_tokens = (const int*)d_in[0];
  const int*   dst        = (const int*)d_in[2];
  const float* emb_in     = (const float*)d_in[3];
  const float* emb_out    = (const float*)d_in[4];
  const float* enc_w_ih0  = (const float*)d_in[5];
  const float* enc_w_ih1  = (const float*)d_in[6];
  const float* enc_w_hh   = (const float*)d_in[7];
  const float* enc_b_ih   = (const float*)d_in[8];
  const float* enc_b_hh   = (const float*)d_in[9];
  const float* dec_w_ih0  = (const float*)d_in[10];
  const float* dec_w_hh0  = (const float*)d_in[11];
  const float* dec_b_ih0  = (const float*)d_in[12];
  const float* dec_b_hh0  = (const float*)d_in[13];
  const float* dec_w_ih1  = (const float*)d_in[14];
  const float* dec_w_hh1  = (const float*)d_in[15];
  const float* dec_b_ih1  = (const float*)d_in[16];
  const float* dec_b_hh1  = (const float*)d_in[17];
  const float* attn_w     = (const float*)d_in[18];
  const float* pred_w     = (const float*)d_in[19];
  const float* pred_b     = (const float*)d_in[20];
  float* out = (float*)d_out;

  float* ws     = (float*)d_ws;
  float* bufA   = ws;                  // 4,194,304 (emb / l0out / dst emb / houts)
  float* GT     = ws + 4194304;        // 16,777,216 transposed gates
  float* encOut = ws + 20971520;       // 4,194,304 ([b][s][h])
  float* rFeed  = ws + 25165824;       // 129*32768 = 4,227,072 (shared w/ rEnc)
  float* rEnc   = rFeed;               //   enc ring (enc dispatches only)
  float* rH0    = ws + 29392896;       // 4,227,072
  float* rH1    = ws + 33619968;       // 4,227,072
  float* rCtx   = ws + 37847040;       // 128*32768 = 4,194,304
  float* c0T    = ws + 42041344;       // 32,768
  float* c1T    = ws + 42074112;       // 32,768
  unsigned* barA = (unsigned*)(ws + 42106880);   // 3 x 8192 uints
  unsigned* barB = barA + 8192;
  unsigned* barC = barB + 8192;
  float* houts  = bufA;

  hipMemsetAsync(barA, 0, 3 * 8192 * sizeof(unsigned), stream);
  hipMemsetAsync(rFeed, 0, 32768 * sizeof(float), stream);  // slot 0: zeros (enc h init + dec feed init)

  // ---- Encoder ----
  k_embed<<<dim3(8192), 128, 0, stream>>>(emb_in, src_tokens, bufA, SS);
  k_gemm<1><<<dim3(16, 64), 256, 0, stream>>>(bufA, 512, enc_w_ih0, 512, 0,
                                              enc_b_ih, enc_b_hh, GT, 2048, 512);
  enc_persist<0><<<dim3(NBLK), 256, 0, stream>>>(GT, enc_w_hh, rEnc, bufA, rH0, c0T, barA);
  k_gemm<1><<<dim3(16, 64), 256, 0, stream>>>(bufA, 512, enc_w_ih1, 512, 0,
                                              enc_b_ih + 2048, enc_b_hh + 2048, GT, 2048, 512);
  enc_persist<1><<<dim3(NBLK), 256, 0, stream>>>(GT, enc_w_hh + 2 * 1024 * 256, rEnc,
                                                 encOut, rH1, c1T, barB);

  // ---- Decoder precompute (emb part of cell0 gates) ----
  k_embed<<<dim3(8192), 128, 0, stream>>>(emb_out, dst, bufA, TT);
  k_gemm<1><<<dim3(16, 64), 256, 0, stream>>>(bufA, 512, dec_w_ih0, 1024, 0,
                                              dec_b_ih0, dec_b_hh0, GT, 2048, 512);

  // NOTE: enc layers scribbled rEnc(=rFeed) slots 1..128; dec step t writes
  // rFeed slot t+1 (write-through) before its only read at step t+1, and the
  // dec dispatch starts with invalidated caches, so no stale data is seen.
  dec_persist<<<dim3(NBLK), 256, 0, stream>>>(
      GT, dec_w_ih0, dec_w_hh0, dec_w_ih1, dec_w_hh1, dec_b_ih1, dec_b_hh1,
      attn_w, encOut, src_tokens, c0T, c1T, rFeed, rH0, rH1, rCtx, houts, barC);

  // ---- Final projection straight to [B][OUT][T] ----
  k_gemm<2><<<dim3(4, 64), 256, 0, stream>>>(houts, 512, pred_w, 512, 0,
                                             pred_b, nullptr, out, 128, 512);
}

// Round 7
// 14292.247 us; speedup vs baseline: 1.2376x; 1.2376x over previous
//
#include <hip/hip_runtime.h>
#include <hip/hip_bf16.h>

#define SS 128
#define TT 128
#define NBLK 256
#define FSTRIDE 16   // one flag per 64B cacheline

__device__ __forceinline__ float sigf(float x) { return 1.f / (1.f + __expf(-x)); }

// Write-through coherent store (to MALL): producers of cross-block data.
__device__ __forceinline__ void cstore(float* p, float v) {
  __hip_atomic_store(p, v, __ATOMIC_RELAXED, __HIP_MEMORY_SCOPE_AGENT);
}

// ---------------------------------------------------------------------------
// Device-wide barrier, fully decontended: arrival flags AND go flags are one
// cacheline per block (1 writer + 1 reader each; no same-line fan-in).
// Layout: flags[0..NBLK*FSTRIDE) = arrivals, [NBLK*FSTRIDE..2*NBLK*FSTRIDE) = go.
// No ACQUIRE (would invalidate L2) and no RELEASE (would wbl2): data moves via
// write-through cstore; each wave's stores are drained (vmcnt) by the compiler
// before s_barrier inside __syncthreads, plus an explicit vmcnt(0) in thread 0.
__device__ __forceinline__ void gbar(unsigned* flags, unsigned gen) {
  __syncthreads();
  int tid = threadIdx.x;
  unsigned* arr = flags;
  unsigned* go  = flags + NBLK * FSTRIDE;
  if (blockIdx.x == 0) {
    if (tid > 0) {
      int guard = 0;
      while (__hip_atomic_load(&arr[tid * FSTRIDE], __ATOMIC_RELAXED,
                               __HIP_MEMORY_SCOPE_AGENT) < gen &&
             ++guard < (1 << 20))
        __builtin_amdgcn_s_sleep(1);
    }
    __syncthreads();
    __hip_atomic_store(&go[tid * FSTRIDE], gen, __ATOMIC_RELAXED,
                       __HIP_MEMORY_SCOPE_AGENT);   // per-block go lines
  } else {
    if (tid == 0) {
      asm volatile("s_waitcnt vmcnt(0)" ::: "memory");
      __hip_atomic_store(&arr[blockIdx.x * FSTRIDE], gen, __ATOMIC_RELAXED,
                         __HIP_MEMORY_SCOPE_AGENT);
      int guard = 0;
      while (__hip_atomic_load(&go[blockIdx.x * FSTRIDE], __ATOMIC_RELAXED,
                               __HIP_MEMORY_SCOPE_AGENT) < gen &&
             ++guard < (1 << 20))
        __builtin_amdgcn_s_sleep(1);
    }
    __syncthreads();
  }
  asm volatile("" ::: "memory");
}

// ---------------------------------------------------------------------------
// Gate partials over this wave's k-quarter. x via PLAIN cached loads
// ([k][64b] layout, lane=batch, coalesced 256B/row); weights from LDS
// (wave-uniform broadcast). unroll 16 keeps 64 x-loads in flight.
template<int NJ, int NK4, int LDW>
__device__ __forceinline__ void mac_lds(const float* __restrict__ xg,
                                        const float* __restrict__ wl,
                                        float* __restrict__ acc) {
#pragma unroll 16
  for (int k4 = 0; k4 < NK4; ++k4) {
    float x0 = xg[(k4 * 4 + 0) * 64];
    float x1 = xg[(k4 * 4 + 1) * 64];
    float x2 = xg[(k4 * 4 + 2) * 64];
    float x3 = xg[(k4 * 4 + 3) * 64];
#pragma unroll
    for (int j = 0; j < NJ; ++j) {
      const float4 w4 = *(const float4*)(wl + j * LDW + k4 * 4);
      acc[j] += x0 * w4.x + x1 * w4.y + x2 * w4.z + x3 * w4.w;
    }
  }
}

// ---------------------------------------------------------------------------
__global__ void k_embed(const float* __restrict__ emb, const int* __restrict__ toks,
                        float* __restrict__ out, int seqlen) {
  int s = blockIdx.x >> 6, b = blockIdx.x & 63;
  int tok = toks[b * seqlen + s];
  const float4* src = (const float4*)(emb + (size_t)tok * 512);
  float4* dst = (float4*)(out + (size_t)blockIdx.x * 512);
  dst[threadIdx.x] = src[threadIdx.x];
}

// ---------------------------------------------------------------------------
// GEMM C[m][n] = X[m]·W[n] + b1[n] + b2[n].
// MODE 1: write GT[((m>>6)*ldc + n)*64 + (m&63)]   (per-timestep transposed gates)
// MODE 2: write out[((m&63)*512 + n)*128 + (m>>6)] (final [B][OUT][T])
template<int MODE>
__global__ __launch_bounds__(256) void k_gemm(
    const float* __restrict__ X, int ldx,
    const float* __restrict__ W, int ldw, int koff,
    const float* __restrict__ b1, const float* __restrict__ b2,
    float* __restrict__ C, int ldc, int K) {
  __shared__ float Xs[16][132];
  __shared__ float Ws[16][132];
  int m0 = blockIdx.y * 128, n0 = blockIdx.x * 128;
  int tx = threadIdx.x & 15, ty = threadIdx.x >> 4;
  float acc[8][8] = {};
  for (int k0 = 0; k0 < K; k0 += 16) {
    __syncthreads();
#pragma unroll
    for (int j = 0; j < 2; ++j) {
      int f4 = threadIdx.x + j * 256;
      int row = f4 >> 2, kc = (f4 & 3) * 4;
      float4 xv = *(const float4*)&X[(size_t)(m0 + row) * ldx + k0 + kc];
      Xs[kc + 0][row] = xv.x; Xs[kc + 1][row] = xv.y;
      Xs[kc + 2][row] = xv.z; Xs[kc + 3][row] = xv.w;
      float4 wv = *(const float4*)&W[(size_t)(n0 + row) * ldw + koff + k0 + kc];
      Ws[kc + 0][row] = wv.x; Ws[kc + 1][row] = wv.y;
      Ws[kc + 2][row] = wv.z; Ws[kc + 3][row] = wv.w;
    }
    __syncthreads();
#pragma unroll
    for (int kk = 0; kk < 16; ++kk) {
      float a[8], w[8];
      *(float4*)&a[0] = *(const float4*)&Xs[kk][ty * 8];
      *(float4*)&a[4] = *(const float4*)&Xs[kk][ty * 8 + 4];
      *(float4*)&w[0] = *(const float4*)&Ws[kk][tx * 8];
      *(float4*)&w[4] = *(const float4*)&Ws[kk][tx * 8 + 4];
#pragma unroll
      for (int i = 0; i < 8; ++i)
#pragma unroll
        for (int j = 0; j < 8; ++j)
          acc[i][j] += a[i] * w[j];
    }
  }
  float bias[8];
#pragma unroll
  for (int j = 0; j < 8; ++j) {
    int n = n0 + tx * 8 + j;
    bias[j] = (b1 ? b1[n] : 0.f) + (b2 ? b2[n] : 0.f);
  }
  for (int i = 0; i < 8; ++i) {
    int m = m0 + ty * 8 + i;
#pragma unroll
    for (int j = 0; j < 8; ++j) {
      int n = n0 + tx * 8 + j;
      float v = acc[i][j] + bias[j];
      if (MODE == 1)
        C[((size_t)(m >> 6) * ldc + n) * 64 + (m & 63)] = v;
      else
        C[((size_t)(m & 63) * 512 + n) * 128 + (m >> 6)] = v;
    }
  }
}

// ---------------------------------------------------------------------------
// Persistent encoder layer. Block nb: dir d=nb>>7, gate rows {nbL+128j}.
// Weight slice in LDS. h state in ring rEnc[t][2 dir][256][64] (slot t read at
// step t, slot t+1 written): cached reads, write-through stores.
template<int LOUT>
__global__ __launch_bounds__(256, 1) void enc_persist(
    const float* __restrict__ GT,     // [128][2048][64] input gates
    const float* __restrict__ whh,    // [2][1024][256] this layer
    float* __restrict__ rEnc,         // [129][2][256][64] ring
    float* __restrict__ lout,
    float* __restrict__ hFin,         // [512][64] (decoder h init, dir-concat)
    float* __restrict__ cFin,         // [512][64]
    unsigned* bar) {
  int nb = blockIdx.x;
  int d = nb >> 7, nbL = nb & 127;
  int tid = threadIdx.x;
  int lane = tid & 63;
  int wv = __builtin_amdgcn_readfirstlane(tid >> 6);
  __shared__ float wE[8][256];          // 8 KB weight slice
  __shared__ float pt[4][8][64];
  for (int idx = tid; idx < 512; idx += 256) {
    int j = idx >> 6, q = idx & 63;
    int row = d * 1024 + nbL + 128 * j;
    *(float4*)&wE[j][q * 4] = *(const float4*)&whh[(size_t)row * 256 + q * 4];
  }
  __syncthreads();

  float creg = 0.f;
  int b = tid & 63, hi = tid >> 6;
  int hu = nbL + hi * 128;

  for (int t = 0; t < SS; ++t) {
    int s = d ? (SS - 1 - t) : t;
    float gi[4];
    if (tid < 128) {
#pragma unroll
      for (int g = 0; g < 4; ++g)
        gi[g] = GT[((size_t)s * 2048 + d * 1024 + g * 256 + hu) * 64 + b];
    }
    if (t > 0) {
      const float* xg = rEnc + (size_t)t * 32768 + d * 16384 + wv * 4096 + lane;
      float acc[8] = {};
      mac_lds<8, 16, 256>(xg, &wE[0][wv * 64], acc);
#pragma unroll
      for (int j = 0; j < 8; ++j) pt[wv][j][lane] = acc[j];
    }
    __syncthreads();
    if (tid < 128) {
      float g4[4];
#pragma unroll
      for (int g = 0; g < 4; ++g) {
        float sum = gi[g];
        if (t > 0)
          sum += pt[0][2 * g + hi][b] + pt[1][2 * g + hi][b] +
                 pt[2][2 * g + hi][b] + pt[3][2 * g + hi][b];
        g4[g] = sum;
      }
      float ig = sigf(g4[0]), fg = sigf(g4[1]), gg = tanhf(g4[2]), og = sigf(g4[3]);
      creg = fg * creg + ig * gg;
      float hn = og * tanhf(creg);
      cstore(&rEnc[(size_t)(t + 1) * 32768 + d * 16384 + hu * 64 + b], hn);
      if (LOUT == 0)
        lout[((size_t)s * 64 + b) * 512 + d * 256 + hu] = hn;
      else
        lout[(size_t)b * 65536 + (size_t)s * 512 + d * 256 + hu] = hn;
      if (t == SS - 1) {
        cstore(&hFin[(d * 256 + hu) * 64 + b], hn);
        cFin[(d * 256 + hu) * 64 + b] = creg;
      }
    }
    if (t < SS - 1) gbar(bar, (unsigned)(t + 1));
  }
}

// ---------------------------------------------------------------------------
// Persistent decoder: 128 steps x 4 phases. Weights (72 KB) in LDS.
// State rings (slot t+1 written at step t; slot 0 = init):
//   rFeed[129][512][64], rH0[129][512][64], rH1[129][512][64], rCtx[128][512][64]
__global__ __launch_bounds__(256, 1) void dec_persist(
    const float* __restrict__ GdT,    // [128][2048][64] emb gates (+biases)
    const float* __restrict__ w_ih0,  // [2048][1024]
    const float* __restrict__ w_hh0,  // [2048][512]
    const float* __restrict__ w_ih1,  // [2048][512]
    const float* __restrict__ w_hh1,  // [2048][512]
    const float* __restrict__ b_ih1, const float* __restrict__ b_hh1,
    const float* __restrict__ attn_w, // [512][1024]
    const float* __restrict__ enc_out,// [64][128][512] batch-major
    const int* __restrict__ src_tokens,
    const float* __restrict__ c0T, const float* __restrict__ c1T,  // [512][64]
    float* __restrict__ rFeed, float* __restrict__ rH0,
    float* __restrict__ rH1, float* __restrict__ rCtx,
    float* __restrict__ houts,        // [8192][512] row-major
    unsigned* bar) {
  int nb = blockIdx.x;
  int tid = threadIdx.x;
  int lane = tid & 63;
  int wv = __builtin_amdgcn_readfirstlane(tid >> 6);
  __shared__ float wA[8][1024];       // 32 KB
  __shared__ float wB[8][1024];       // 32 KB
  __shared__ float wD[2][1024];       // 8 KB
  __shared__ float pt[4][8][64];
  __shared__ float h1s[512];
  __shared__ float sc[128];

  // ---- stage weights into LDS (once) ----
  for (int idx = tid; idx < 2048; idx += 256) {
    int j = idx >> 8, q = idx & 255;
    int k = q * 4, row = nb + 256 * j;
    float4 v = (k < 512)
        ? *(const float4*)&w_ih0[(size_t)row * 1024 + 512 + k]
        : *(const float4*)&w_hh0[(size_t)row * 512 + (k - 512)];
    *(float4*)&wA[j][k] = v;
  }
  for (int idx = tid; idx < 2048; idx += 256) {
    int j = idx >> 8, q = idx & 255;
    int k = q * 4, row = nb + 256 * j;
    float4 v = (k < 512)
        ? *(const float4*)&w_ih1[(size_t)row * 512 + k]
        : *(const float4*)&w_hh1[(size_t)row * 512 + (k - 512)];
    *(float4*)&wB[j][k] = v;
  }
  for (int idx = tid; idx < 512; idx += 256) {
    int j = idx >> 8, q = idx & 255;
    *(float4*)&wD[j][q * 4] =
        *(const float4*)&attn_w[(size_t)(nb * 2 + j) * 1024 + q * 4];
  }
  __syncthreads();

  int bb = tid & 63, hi = tid >> 6;
  int hu = nb + (hi & 1) * 256;
  float c0r = 0.f, c1r = 0.f;
  if (tid < 128) { c0r = c0T[hu * 64 + bb]; c1r = c1T[hu * 64 + bb]; }

  for (int t = 0; t < TT; ++t) {
    unsigned gb = (unsigned)(t * 4);
    size_t cur = (size_t)t * 32768, nxt = (size_t)(t + 1) * 32768;
    // ---- A: cell0 gates (x = [feed | h0] from slot t) ----
    float giA[4];
    if (tid < 128) {
#pragma unroll
      for (int g = 0; g < 4; ++g)
        giA[g] = GdT[((size_t)t * 2048 + g * 512 + hu) * 64 + bb];
    }
    {
      const float* xg = (wv < 2) ? rFeed + cur + wv * 16384 + lane
                                 : rH0 + cur + (wv - 2) * 16384 + lane;
      float acc[8] = {};
      mac_lds<8, 64, 1024>(xg, &wA[0][wv * 256], acc);
#pragma unroll
      for (int j = 0; j < 8; ++j) pt[wv][j][lane] = acc[j];
    }
    __syncthreads();
    if (tid < 128) {
      float g4[4];
#pragma unroll
      for (int g = 0; g < 4; ++g)
        g4[g] = pt[0][2 * g + hi][bb] + pt[1][2 * g + hi][bb] +
                pt[2][2 * g + hi][bb] + pt[3][2 * g + hi][bb] + giA[g];
      float ig = sigf(g4[0]), fg = sigf(g4[1]), gg = tanhf(g4[2]), og = sigf(g4[3]);
      c0r = fg * c0r + ig * gg;
      float hn = og * tanhf(c0r);
      cstore(&rH0[nxt + hu * 64 + bb], hn);
    }
    gbar(bar, gb + 1);
    // ---- B: cell1 gates (x = [h0 slot t+1 | h1 slot t]) ----
    {
      const float* xg = (wv < 2) ? rH0 + nxt + wv * 16384 + lane
                                 : rH1 + cur + (wv - 2) * 16384 + lane;
      float acc[8] = {};
      mac_lds<8, 64, 1024>(xg, &wB[0][wv * 256], acc);
#pragma unroll
      for (int j = 0; j < 8; ++j) pt[wv][j][lane] = acc[j];
    }
    __syncthreads();
    if (tid < 128) {
      float g4[4];
#pragma unroll
      for (int g = 0; g < 4; ++g)
        g4[g] = pt[0][2 * g + hi][bb] + pt[1][2 * g + hi][bb] +
                pt[2][2 * g + hi][bb] + pt[3][2 * g + hi][bb] +
                b_ih1[g * 512 + hu] + b_hh1[g * 512 + hu];
      float ig = sigf(g4[0]), fg = sigf(g4[1]), gg = tanhf(g4[2]), og = sigf(g4[3]);
      c1r = fg * c1r + ig * gg;
      float hn = og * tanhf(c1r);
      cstore(&rH1[nxt + hu * 64 + bb], hn);
    }
    gbar(bar, gb + 2);
    // ---- C: attention (blocks 0..63, one per batch; enc_out [b][s][h]) ----
    if (nb < 64) {
      const float* h1c = rH1 + nxt;
      const float* eb = enc_out + (size_t)nb * 65536;
      for (int i = tid; i < 512; i += 256)
        h1s[i] = h1c[i * 64 + nb];
      __syncthreads();
      {
        int s2 = tid >> 1, half = tid & 1;
        const float* er = eb + (size_t)s2 * 512 + half * 256;
        const float* hh = h1s + half * 256;
        float a = 0.f;
#pragma unroll 8
        for (int k = 0; k < 256; k += 4) {
          float4 ev = *(const float4*)&er[k];
          a += ev.x * hh[k] + ev.y * hh[k + 1] + ev.z * hh[k + 2] + ev.w * hh[k + 3];
        }
        a += __shfl_xor(a, 1);
        if (!half) sc[s2] = (src_tokens[nb * SS + s2] == 0) ? -1e30f : a;
      }
      __syncthreads();
      if (tid < 64) {
        float m = fmaxf(sc[tid], sc[tid + 64]);
        for (int off = 32; off; off >>= 1) m = fmaxf(m, __shfl_xor(m, off));
        float e0 = __expf(sc[tid] - m), e1 = __expf(sc[tid + 64] - m);
        float ssum = e0 + e1;
        for (int off = 32; off; off >>= 1) ssum += __shfl_xor(ssum, off);
        float inv = 1.f / ssum;
        sc[tid] = e0 * inv; sc[tid + 64] = e1 * inv;
      }
      __syncthreads();
      float a0 = 0.f, a1 = 0.f;
      for (int s2 = 0; s2 < 128; ++s2) {
        float p_ = sc[s2];
        const float* er = eb + (size_t)s2 * 512;
        a0 += p_ * er[tid];
        a1 += p_ * er[tid + 256];
      }
      cstore(&rCtx[cur + tid * 64 + nb], a0);
      cstore(&rCtx[cur + (tid + 256) * 64 + nb], a1);
    }
    gbar(bar, gb + 3);
    // ---- D: outproj tanh([ctx slot t | h1 slot t+1]@attn_w^T) ----
    {
      const float* xg = (wv < 2) ? rCtx + cur + wv * 16384 + lane
                                 : rH1 + nxt + (wv - 2) * 16384 + lane;
      float acc[2] = {};
      mac_lds<2, 64, 1024>(xg, &wD[0][wv * 256], acc);
      pt[wv][0][lane] = acc[0];
      pt[wv][1][lane] = acc[1];
    }
    __syncthreads();
    if (tid < 128) {
      int o = nb * 2 + hi;
      float v = tanhf(pt[0][hi][bb] + pt[1][hi][bb] + pt[2][hi][bb] + pt[3][hi][bb]);
      cstore(&rFeed[nxt + o * 64 + bb], v);
      houts[((size_t)t * 64 + bb) * 512 + o] = v;
    }
    if (t < TT - 1) gbar(bar, gb + 4);
  }
}

// ---------------------------------------------------------------------------
extern "C" void kernel_launch(void* const* d_in, const int* in_sizes, int n_in,
                              void* d_out, int out_size, void* d_ws, size_t ws_size,
                              hipStream_t stream) {
  const int*   src_tokens = (const int*)d_in[0];
  const int*   dst        = (const int*)d_in[2];
  const float* emb_in     = (const float*)d_in[3];
  const float* emb_out    = (const float*)d_in[4];
  const float* enc_w_ih0  = (const float*)d_in[5];
  const float* enc_w_ih1  = (const float*)d_in[6];
  const float* enc_w_hh   = (const float*)d_in[7];
  const float* enc_b_ih   = (const float*)d_in[8];
  const float* enc_b_hh   = (const float*)d_in[9];
  const float* dec_w_ih0  = (const float*)d_in[10];
  const float* dec_w_hh0  = (const float*)d_in[11];
  const float* dec_b_ih0  = (const float*)d_in[12];
  const float* dec_b_hh0  = (const float*)d_in[13];
  const float* dec_w_ih1  = (const float*)d_in[14];
  const float* dec_w_hh1  = (const float*)d_in[15];
  const float* dec_b_ih1  = (const float*)d_in[16];
  const float* dec_b_hh1  = (const float*)d_in[17];
  const float* attn_w     = (const float*)d_in[18];
  const float* pred_w     = (const float*)d_in[19];
  const float* pred_b     = (const float*)d_in[20];
  float* out = (float*)d_out;

  float* ws     = (float*)d_ws;
  float* bufA   = ws;                  // 4,194,304 (emb / l0out / dst emb / houts)
  float* GT     = ws + 4194304;        // 16,777,216 transposed gates
  float* encOut = ws + 20971520;       // 4,194,304 ([b][s][h])
  float* rFeed  = ws + 25165824;       // 129*32768 = 4,227,072 (shared w/ rEnc)
  float* rEnc   = rFeed;               //   enc ring (enc dispatches only)
  float* rH0    = ws + 29392896;       // 4,227,072
  float* rH1    = ws + 33619968;       // 4,227,072
  float* rCtx   = ws + 37847040;       // 128*32768 = 4,194,304
  float* c0T    = ws + 42041344;       // 32,768
  float* c1T    = ws + 42074112;       // 32,768
  unsigned* barA = (unsigned*)(ws + 42106880);   // 3 x (2*256*16) uints
  unsigned* barB = barA + 8192;
  unsigned* barC = barB + 8192;
  float* houts  = bufA;

  hipMemsetAsync(barA, 0, 3 * 8192 * sizeof(unsigned), stream);
  hipMemsetAsync(rFeed, 0, 32768 * sizeof(float), stream);  // slot 0: zeros (enc h init + dec feed init)

  // ---- Encoder ----
  k_embed<<<dim3(8192), 128, 0, stream>>>(emb_in, src_tokens, bufA, SS);
  k_gemm<1><<<dim3(16, 64), 256, 0, stream>>>(bufA, 512, enc_w_ih0, 512, 0,
                                              enc_b_ih, enc_b_hh, GT, 2048, 512);
  enc_persist<0><<<dim3(NBLK), 256, 0, stream>>>(GT, enc_w_hh, rEnc, bufA, rH0, c0T, barA);
  k_gemm<1><<<dim3(16, 64), 256, 0, stream>>>(bufA, 512, enc_w_ih1, 512, 0,
                                              enc_b_ih + 2048, enc_b_hh + 2048, GT, 2048, 512);
  enc_persist<1><<<dim3(NBLK), 256, 0, stream>>>(GT, enc_w_hh + 2 * 1024 * 256, rEnc,
                                                 encOut, rH1, c1T, barB);

  // ---- Decoder precompute (emb part of cell0 gates) ----
  k_embed<<<dim3(8192), 128, 0, stream>>>(emb_out, dst, bufA, TT);
  k_gemm<1><<<dim3(16, 64), 256, 0, stream>>>(bufA, 512, dec_w_ih0, 1024, 0,
                                              dec_b_ih0, dec_b_hh0, GT, 2048, 512);

  // NOTE: enc layers scribbled rEnc(=rFeed) slots 1..128; dec step t writes
  // rFeed slot t+1 (write-through) before its only read at step t+1, and the
  // dec dispatch starts with invalidated caches, so no stale data is seen.
  dec_persist<<<dim3(NBLK), 256, 0, stream>>>(
      GT, dec_w_ih0, dec_w_hh0, dec_w_ih1, dec_w_hh1, dec_b_ih1, dec_b_hh1,
      attn_w, encOut, src_tokens, c0T, c1T, rFeed, rH0, rH1, rCtx, houts, barC);

  // ---- Final projection straight to [B][OUT][T] ----
  k_gemm<2><<<dim3(4, 64), 256, 0, stream>>>(houts, 512, pred_w, 512, 0,
                                             pred_b, nullptr, out, 128, 512);
}

// Round 8
// 6319.897 us; speedup vs baseline: 2.7989x; 2.2615x over previous
//
#include <hip/hip_runtime.h>
#include <hip/hip_bf16.h>

#define SS 128
#define TT 128
#define NBLK 256
#define FSTRIDE 16   // one flag per 64B cacheline

typedef __attribute__((ext_vector_type(8))) short bf16x8;
typedef __attribute__((ext_vector_type(4))) float f32x4;
typedef unsigned short ushort_t;

__device__ __forceinline__ float sigf(float x) { return 1.f / (1.f + __expf(-x)); }

__device__ __forceinline__ ushort_t f2bf(float f) {   // RNE f32 -> bf16
  unsigned b = __builtin_bit_cast(unsigned, f);
  return (ushort_t)((b + 0x7FFFu + ((b >> 16) & 1u)) >> 16);
}
__device__ __forceinline__ float bf2f(ushort_t u) {
  return __builtin_bit_cast(float, (unsigned)u << 16);
}

// Write-through coherent bf16 store (to MALL): cross-block producers.
__device__ __forceinline__ void cstoreh(ushort_t* p, ushort_t v) {
  __hip_atomic_store(p, v, __ATOMIC_RELAXED, __HIP_MEMORY_SCOPE_AGENT);
}

// ---------------------------------------------------------------------------
// Device-wide barrier, fully decontended (R7): per-block arrival + go lines.
// Ring data is write-through; consumers use plain cached loads on fresh ring
// addresses (each ring address written once/dispatch before its only read).
__device__ __forceinline__ void gbar(unsigned* flags, unsigned gen) {
  __syncthreads();
  int tid = threadIdx.x;
  unsigned* arr = flags;
  unsigned* go  = flags + NBLK * FSTRIDE;
  if (blockIdx.x == 0) {
    if (tid > 0) {
      int guard = 0;
      while (__hip_atomic_load(&arr[tid * FSTRIDE], __ATOMIC_RELAXED,
                               __HIP_MEMORY_SCOPE_AGENT) < gen &&
             ++guard < (1 << 20))
        __builtin_amdgcn_s_sleep(1);
    }
    __syncthreads();
    __hip_atomic_store(&go[tid * FSTRIDE], gen, __ATOMIC_RELAXED,
                       __HIP_MEMORY_SCOPE_AGENT);
  } else {
    if (tid == 0) {
      asm volatile("s_waitcnt vmcnt(0)" ::: "memory");
      __hip_atomic_store(&arr[blockIdx.x * FSTRIDE], gen, __ATOMIC_RELAXED,
                         __HIP_MEMORY_SCOPE_AGENT);
      int guard = 0;
      while (__hip_atomic_load(&go[blockIdx.x * FSTRIDE], __ATOMIC_RELAXED,
                               __HIP_MEMORY_SCOPE_AGENT) < gen &&
             ++guard < (1 << 20))
        __builtin_amdgcn_s_sleep(1);
    }
    __syncthreads();
  }
  asm volatile("" ::: "memory");
}

// ---------------------------------------------------------------------------
__global__ void k_embed(const float* __restrict__ emb, const int* __restrict__ toks,
                        float* __restrict__ out, int seqlen) {
  int s = blockIdx.x >> 6, b = blockIdx.x & 63;
  int tok = toks[b * seqlen + s];
  const float4* src = (const float4*)(emb + (size_t)tok * 512);
  float4* dst = (float4*)(out + (size_t)blockIdx.x * 512);
  dst[threadIdx.x] = src[threadIdx.x];
}

// ---------------------------------------------------------------------------
// fp32 GEMM (input-gate precompute + final projection), unchanged.
// MODE 1: C[((m>>6)*ldc + n)*64 + (m&63)]   MODE 2: out[((m&63)*512+n)*128+(m>>6)]
template<int MODE>
__global__ __launch_bounds__(256) void k_gemm(
    const float* __restrict__ X, int ldx,
    const float* __restrict__ W, int ldw, int koff,
    const float* __restrict__ b1, const float* __restrict__ b2,
    float* __restrict__ C, int ldc, int K) {
  __shared__ float Xs[16][132];
  __shared__ float Ws[16][132];
  int m0 = blockIdx.y * 128, n0 = blockIdx.x * 128;
  int tx = threadIdx.x & 15, ty = threadIdx.x >> 4;
  float acc[8][8] = {};
  for (int k0 = 0; k0 < K; k0 += 16) {
    __syncthreads();
#pragma unroll
    for (int j = 0; j < 2; ++j) {
      int f4 = threadIdx.x + j * 256;
      int row = f4 >> 2, kc = (f4 & 3) * 4;
      float4 xv = *(const float4*)&X[(size_t)(m0 + row) * ldx + k0 + kc];
      Xs[kc + 0][row] = xv.x; Xs[kc + 1][row] = xv.y;
      Xs[kc + 2][row] = xv.z; Xs[kc + 3][row] = xv.w;
      float4 wv = *(const float4*)&W[(size_t)(n0 + row) * ldw + koff + k0 + kc];
      Ws[kc + 0][row] = wv.x; Ws[kc + 1][row] = wv.y;
      Ws[kc + 2][row] = wv.z; Ws[kc + 3][row] = wv.w;
    }
    __syncthreads();
#pragma unroll
    for (int kk = 0; kk < 16; ++kk) {
      float a[8], w[8];
      *(float4*)&a[0] = *(const float4*)&Xs[kk][ty * 8];
      *(float4*)&a[4] = *(const float4*)&Xs[kk][ty * 8 + 4];
      *(float4*)&w[0] = *(const float4*)&Ws[kk][tx * 8];
      *(float4*)&w[4] = *(const float4*)&Ws[kk][tx * 8 + 4];
#pragma unroll
      for (int i = 0; i < 8; ++i)
#pragma unroll
        for (int j = 0; j < 8; ++j)
          acc[i][j] += a[i] * w[j];
    }
  }
  float bias[8];
#pragma unroll
  for (int j = 0; j < 8; ++j) {
    int n = n0 + tx * 8 + j;
    bias[j] = (b1 ? b1[n] : 0.f) + (b2 ? b2[n] : 0.f);
  }
  for (int i = 0; i < 8; ++i) {
    int m = m0 + ty * 8 + i;
#pragma unroll
    for (int j = 0; j < 8; ++j) {
      int n = n0 + tx * 8 + j;
      float v = acc[i][j] + bias[j];
      if (MODE == 1)
        C[((size_t)(m >> 6) * ldc + n) * 64 + (m & 63)] = v;
      else
        C[((size_t)(m & 63) * 512 + n) * 128 + (m >> 6)] = v;
    }
  }
}

// ---------------------------------------------------------------------------
// MFMA fragment conventions (mfma_f32_16x16x32_bf16):
//   A[16m][32k]: lane l holds m=l&15, k=(l>>4)*8+i  (8 bf16, k-contiguous)
//   B[32k][16n]: lane l holds n=l&15, k=(l>>4)*8+i  (8 bf16, k-contiguous)
//   D[16m][16n]: lane l reg r holds m=(l>>4)*4+r, n=l&15   [m89-verified]
// Per block: G[16 rows][64 b] = W[16][K]*X[K][64]; wave wv owns batches
// wv*16..+15 (full K). Rows m: 0-3 = gates i,f,g,o of hu0; 4-7 = of hu1;
// 8-15 zero-pad. Epilogue: lanes 0-31, regs = the 4 gates of one (hu,b).

// Persistent encoder layer: K=256, ring rEnc[129][2][64][256] bf16.
template<int LOUT>
__global__ __launch_bounds__(256, 1) void enc_persist(
    const float* __restrict__ GT,     // [128][2048][64] input gates fp32
    const float* __restrict__ whh,    // [2][1024][256] this layer fp32
    ushort_t* __restrict__ ringE,     // [129][2][64][256] bf16
    float* __restrict__ lout,
    ushort_t* __restrict__ hFin,      // dec ring slot0 [64][1024]; write 512+d*256+hu
    float* __restrict__ cFin,         // [512][64] fp32
    unsigned* bar) {
  int nb = blockIdx.x;
  int d = nb >> 7, nbL = nb & 127;
  int tid = threadIdx.x;
  int lane = tid & 63;
  int wv = __builtin_amdgcn_readfirstlane(tid >> 6);
  int l16 = lane & 15, kg = lane >> 4;
  __shared__ ushort_t wE[16 * 264];   // [16 m][256 k] bf16, row stride 264 (16B-aligned, bank-staggered)

  for (int idx = tid; idx < 16 * 256; idx += 256) {
    int m = idx >> 8, k = idx & 255;
    float v = 0.f;
    if (m < 8)
      v = whh[(size_t)d * 262144 +
              (size_t)((m & 3) * 256 + nbL + 128 * (m >> 2)) * 256 + k];
    wE[m * 264 + k] = f2bf(v);
  }
  __syncthreads();

  int b = wv * 16 + l16;
  int hu = nbL + 128 * kg;            // valid for epilogue lanes (<32)
  float creg = 0.f;
  const ushort_t* wp = wE + l16 * 264 + kg * 8;

  for (int t = 0; t < SS; ++t) {
    int s = d ? (SS - 1 - t) : t;
    f32x4 acc = {0.f, 0.f, 0.f, 0.f};
    const ushort_t* xb = ringE + ((size_t)(t * 2 + d) * 64 + b) * 256 + kg * 8;
#pragma unroll
    for (int ks = 0; ks < 8; ++ks) {
      bf16x8 af = *(const bf16x8*)(wp + ks * 32);
      bf16x8 bf = *(const bf16x8*)(xb + ks * 32);
      acc = __builtin_amdgcn_mfma_f32_16x16x32_bf16(af, bf, acc, 0, 0, 0);
    }
    if (lane < 32) {
      float g4[4];
#pragma unroll
      for (int r = 0; r < 4; ++r)
        g4[r] = acc[r] + GT[((size_t)s * 2048 + d * 1024 + r * 256 + hu) * 64 + b];
      float ig = sigf(g4[0]), fg = sigf(g4[1]), gg = tanhf(g4[2]), og = sigf(g4[3]);
      creg = fg * creg + ig * gg;
      float hn = og * tanhf(creg);
      cstoreh(&ringE[((size_t)((t + 1) * 2 + d) * 64 + b) * 256 + hu], f2bf(hn));
      if (LOUT == 0)
        lout[((size_t)s * 64 + b) * 512 + d * 256 + hu] = hn;
      else
        lout[(size_t)b * 65536 + (size_t)s * 512 + d * 256 + hu] = hn;
      if (t == SS - 1) {
        hFin[(size_t)b * 1024 + 512 + d * 256 + hu] = f2bf(hn);
        cFin[(d * 256 + hu) * 64 + b] = creg;
      }
    }
    if (t < SS - 1) gbar(bar, (unsigned)(t + 1));
  }
}

// ---------------------------------------------------------------------------
// Persistent decoder: 128 steps x {cell0, cell1, attention, outproj}.
// bf16 rings [slot][64 b][1024 k]: r0=[feed|h0], r1=[h0|h1], r2=[ctx|h1].
__global__ __launch_bounds__(256, 1) void dec_persist(
    const float* __restrict__ GdT,    // [128][2048][64] emb gates fp32
    const float* __restrict__ w_ih0, const float* __restrict__ w_hh0,
    const float* __restrict__ w_ih1, const float* __restrict__ w_hh1,
    const float* __restrict__ b_ih1, const float* __restrict__ b_hh1,
    const float* __restrict__ attn_w,
    const float* __restrict__ enc_out,   // [64][128][512] fp32
    const int* __restrict__ src_tokens,
    const float* __restrict__ c0T, const float* __restrict__ c1T,  // [512][64]
    ushort_t* __restrict__ r0, ushort_t* __restrict__ r1,
    ushort_t* __restrict__ r2,
    float* __restrict__ houts,        // [8192][512] fp32
    unsigned* bar) {
  int nb = blockIdx.x;
  int tid = threadIdx.x;
  int lane = tid & 63;
  int wv = __builtin_amdgcn_readfirstlane(tid >> 6);
  int l16 = lane & 15, kg = lane >> 4;
  __shared__ ushort_t wAl[16 * 1032];   // 33KB each, stride 1032 bf16 (16B-aligned)
  __shared__ ushort_t wBl[16 * 1032];
  __shared__ ushort_t wDl[16 * 1032];
  __shared__ float h1s[512];
  __shared__ float sc[128];

  // ---- stage bf16 weights (once). Rows 0-3: gates of hu=nb; 4-7: hu=nb+256.
  for (int idx = tid; idx < 16384; idx += 256) {
    int m = idx >> 10, k = idx & 1023;
    float va = 0.f, vb = 0.f, vd = 0.f;
    if (m < 8) {
      int row = (m & 3) * 512 + nb + 256 * (m >> 2);
      va = (k < 512) ? w_ih0[(size_t)row * 1024 + 512 + k]
                     : w_hh0[(size_t)row * 512 + (k - 512)];
      vb = (k < 512) ? w_ih1[(size_t)row * 512 + k]
                     : w_hh1[(size_t)row * 512 + (k - 512)];
    }
    if (m < 2) vd = attn_w[(size_t)(nb * 2 + m) * 1024 + k];
    wAl[m * 1032 + k] = f2bf(va);
    wBl[m * 1032 + k] = f2bf(vb);
    wDl[m * 1032 + k] = f2bf(vd);
  }
  __syncthreads();

  int b = wv * 16 + l16;
  int hu = nb + 256 * kg;             // valid for epilogue lanes (<32)
  float c0r = 0.f, c1r = 0.f, bias1[4] = {0.f, 0.f, 0.f, 0.f};
  if (lane < 32) {
    c0r = c0T[hu * 64 + b];
    c1r = c1T[hu * 64 + b];
#pragma unroll
    for (int r = 0; r < 4; ++r)
      bias1[r] = b_ih1[r * 512 + hu] + b_hh1[r * 512 + hu];
  }
  const ushort_t* wpA = wAl + l16 * 1032 + kg * 8;
  const ushort_t* wpB = wBl + l16 * 1032 + kg * 8;
  const ushort_t* wpD = wDl + l16 * 1032 + kg * 8;

  for (int t = 0; t < TT; ++t) {
    unsigned gb = (unsigned)(t * 4);
    size_t sC = (size_t)t * 65536, sN = (size_t)(t + 1) * 65536;
    // ---- A: cell0 (x = [feed(t)|h0(t)] = r0 slot t) ----
    {
      f32x4 acc = {0.f, 0.f, 0.f, 0.f};
      const ushort_t* xb = r0 + sC + (size_t)b * 1024 + kg * 8;
#pragma unroll 8
      for (int ks = 0; ks < 32; ++ks) {
        bf16x8 af = *(const bf16x8*)(wpA + ks * 32);
        bf16x8 bf = *(const bf16x8*)(xb + ks * 32);
        acc = __builtin_amdgcn_mfma_f32_16x16x32_bf16(af, bf, acc, 0, 0, 0);
      }
      if (lane < 32) {
        float g4[4];
#pragma unroll
        for (int r = 0; r < 4; ++r)
          g4[r] = acc[r] + GdT[((size_t)t * 2048 + r * 512 + hu) * 64 + b];
        float ig = sigf(g4[0]), fg = sigf(g4[1]), gg = tanhf(g4[2]), og = sigf(g4[3]);
        c0r = fg * c0r + ig * gg;
        float hn = og * tanhf(c0r);
        ushort_t hb = f2bf(hn);
        cstoreh(&r0[sN + (size_t)b * 1024 + 512 + hu], hb);
        cstoreh(&r1[sC + (size_t)b * 1024 + hu], hb);
      }
    }
    gbar(bar, gb + 1);
    // ---- B: cell1 (x = [h0(t)|h1(t-1)] = r1 slot t) ----
    {
      f32x4 acc = {0.f, 0.f, 0.f, 0.f};
      const ushort_t* xb = r1 + sC + (size_t)b * 1024 + kg * 8;
#pragma unroll 8
      for (int ks = 0; ks < 32; ++ks) {
        bf16x8 af = *(const bf16x8*)(wpB + ks * 32);
        bf16x8 bf = *(const bf16x8*)(xb + ks * 32);
        acc = __builtin_amdgcn_mfma_f32_16x16x32_bf16(af, bf, acc, 0, 0, 0);
      }
      if (lane < 32) {
        float g4[4];
#pragma unroll
        for (int r = 0; r < 4; ++r)
          g4[r] = acc[r] + bias1[r];
        float ig = sigf(g4[0]), fg = sigf(g4[1]), gg = tanhf(g4[2]), og = sigf(g4[3]);
        c1r = fg * c1r + ig * gg;
        float hn = og * tanhf(c1r);
        ushort_t hb = f2bf(hn);
        cstoreh(&r1[sN + (size_t)b * 1024 + 512 + hu], hb);
        cstoreh(&r2[sC + (size_t)b * 1024 + 512 + hu], hb);
      }
    }
    gbar(bar, gb + 2);
    // ---- C: attention (blocks 0..63, one per batch; fp32) ----
    if (nb < 64) {
      const ushort_t* h1b = r1 + sN + (size_t)nb * 1024 + 512;
      const float* eb = enc_out + (size_t)nb * 65536;
      for (int i = tid; i < 512; i += 256) h1s[i] = bf2f(h1b[i]);
      __syncthreads();
      {
        int s2 = tid >> 1, half = tid & 1;
        const float* er = eb + (size_t)s2 * 512 + half * 256;
        const float* hh = h1s + half * 256;
        float a = 0.f;
#pragma unroll 8
        for (int k = 0; k < 256; k += 4) {
          float4 ev = *(const float4*)&er[k];
          a += ev.x * hh[k] + ev.y * hh[k + 1] + ev.z * hh[k + 2] + ev.w * hh[k + 3];
        }
        a += __shfl_xor(a, 1);
        if (!half) sc[s2] = (src_tokens[nb * SS + s2] == 0) ? -1e30f : a;
      }
      __syncthreads();
      if (tid < 64) {
        float m = fmaxf(sc[tid], sc[tid + 64]);
        for (int off = 32; off; off >>= 1) m = fmaxf(m, __shfl_xor(m, off));
        float e0 = __expf(sc[tid] - m), e1 = __expf(sc[tid + 64] - m);
        float ssum = e0 + e1;
        for (int off = 32; off; off >>= 1) ssum += __shfl_xor(ssum, off);
        float inv = 1.f / ssum;
        sc[tid] = e0 * inv; sc[tid + 64] = e1 * inv;
      }
      __syncthreads();
      float a0 = 0.f, a1 = 0.f;
      for (int s2 = 0; s2 < 128; ++s2) {
        float p_ = sc[s2];
        const float* er = eb + (size_t)s2 * 512;
        a0 += p_ * er[tid];
        a1 += p_ * er[tid + 256];
      }
      cstoreh(&r2[sC + (size_t)nb * 1024 + tid], f2bf(a0));
      cstoreh(&r2[sC + (size_t)nb * 1024 + tid + 256], f2bf(a1));
    }
    gbar(bar, gb + 3);
    // ---- D: outproj tanh([ctx|h1] @ attn_w^T) -> feed + houts ----
    {
      f32x4 acc = {0.f, 0.f, 0.f, 0.f};
      const ushort_t* xb = r2 + sC + (size_t)b * 1024 + kg * 8;
#pragma unroll 8
      for (int ks = 0; ks < 32; ++ks) {
        bf16x8 af = *(const bf16x8*)(wpD + ks * 32);
        bf16x8 bf = *(const bf16x8*)(xb + ks * 32);
        acc = __builtin_amdgcn_mfma_f32_16x16x32_bf16(af, bf, acc, 0, 0, 0);
      }
      if (lane < 16) {   // rows 0,1 live in lanes 0-15, regs 0-1
#pragma unroll
        for (int r = 0; r < 2; ++r) {
          int o = nb * 2 + r;
          float v = tanhf(acc[r]);
          cstoreh(&r0[sN + (size_t)b * 1024 + o], f2bf(v));
          houts[((size_t)t * 64 + b) * 512 + o] = v;
        }
      }
    }
    if (t < TT - 1) gbar(bar, gb + 4);
  }
}

// ---------------------------------------------------------------------------
extern "C" void kernel_launch(void* const* d_in, const int* in_sizes, int n_in,
                              void* d_out, int out_size, void* d_ws, size_t ws_size,
                              hipStream_t stream) {
  const int*   src_tokens = (const int*)d_in[0];
  const int*   dst        = (const int*)d_in[2];
  const float* emb_in     = (const float*)d_in[3];
  const float* emb_out    = (const float*)d_in[4];
  const float* enc_w_ih0  = (const float*)d_in[5];
  const float* enc_w_ih1  = (const float*)d_in[6];
  const float* enc_w_hh   = (const float*)d_in[7];
  const float* enc_b_ih   = (const float*)d_in[8];
  const float* enc_b_hh   = (const float*)d_in[9];
  const float* dec_w_ih0  = (const float*)d_in[10];
  const float* dec_w_hh0  = (const float*)d_in[11];
  const float* dec_b_ih0  = (const float*)d_in[12];
  const float* dec_b_hh0  = (const float*)d_in[13];
  const float* dec_w_ih1  = (const float*)d_in[14];
  const float* dec_w_hh1  = (const float*)d_in[15];
  const float* dec_b_ih1  = (const float*)d_in[16];
  const float* dec_b_hh1  = (const float*)d_in[17];
  const float* attn_w     = (const float*)d_in[18];
  const float* pred_w     = (const float*)d_in[19];
  const float* pred_b     = (const float*)d_in[20];
  float* out = (float*)d_out;

  float* ws     = (float*)d_ws;
  float* bufA   = ws;                   // 4,194,304 f (emb / l0out / dst emb / houts)
  float* GT     = ws + 4194304;         // 16,777,216 f (transposed gates)
  float* encOut = ws + 20971520;        // 4,194,304 f ([b][s][h])
  ushort_t* r0   = (ushort_t*)(ws + 25165824);  // 129*64*1024 bf16 = 4,227,072 f
  ushort_t* r1   = (ushort_t*)(ws + 29392896);  // 4,227,072 f
  ushort_t* r2   = (ushort_t*)(ws + 33619968);  // 128 slots = 4,194,304 f
  ushort_t* ringE= (ushort_t*)(ws + 37814272);  // 129*2*64*256 bf16 = 2,113,536 f
  float* c0T    = ws + 39927808;        // 32,768
  float* c1T    = ws + 39960576;        // 32,768
  unsigned* barA = (unsigned*)(ws + 39993344);  // 3 x 8192 uints
  unsigned* barB = barA + 8192;
  unsigned* barC = barB + 8192;
  float* houts  = bufA;

  hipMemsetAsync(barA, 0, 3 * 8192 * sizeof(unsigned), stream);
  hipMemsetAsync(r0, 0, 65536 * sizeof(ushort_t), stream);     // slot 0 (feed=0; h_l0 filled by enc)
  hipMemsetAsync(r1, 0, 65536 * sizeof(ushort_t), stream);     // slot 0 (h_l1 filled by enc)
  hipMemsetAsync(ringE, 0, 32768 * sizeof(ushort_t), stream);  // slot 0 = h(0)=0

  // ---- Encoder ----
  k_embed<<<dim3(8192), 128, 0, stream>>>(emb_in, src_tokens, bufA, SS);
  k_gemm<1><<<dim3(16, 64), 256, 0, stream>>>(bufA, 512, enc_w_ih0, 512, 0,
                                              enc_b_ih, enc_b_hh, GT, 2048, 512);
  enc_persist<0><<<dim3(NBLK), 256, 0, stream>>>(GT, enc_w_hh, ringE, bufA,
                                                 r0, c0T, barA);
  k_gemm<1><<<dim3(16, 64), 256, 0, stream>>>(bufA, 512, enc_w_ih1, 512, 0,
                                              enc_b_ih + 2048, enc_b_hh + 2048, GT, 2048, 512);
  enc_persist<1><<<dim3(NBLK), 256, 0, stream>>>(GT, enc_w_hh + 524288, ringE,
                                                 encOut, r1, c1T, barB);

  // ---- Decoder precompute (emb part of cell0 gates) ----
  k_embed<<<dim3(8192), 128, 0, stream>>>(emb_out, dst, bufA, TT);
  k_gemm<1><<<dim3(16, 64), 256, 0, stream>>>(bufA, 512, dec_w_ih0, 1024, 0,
                                              dec_b_ih0, dec_b_hh0, GT, 2048, 512);

  // ---- Decoder (persistent, MFMA) ----
  dec_persist<<<dim3(NBLK), 256, 0, stream>>>(
      GT, dec_w_ih0, dec_w_hh0, dec_w_ih1, dec_w_hh1, dec_b_ih1, dec_b_hh1,
      attn_w, encOut, src_tokens, c0T, c1T, r0, r1, r2, houts, barC);

  // ---- Final projection straight to [B][OUT][T] ----
  k_gemm<2><<<dim3(4, 64), 256, 0, stream>>>(houts, 512, pred_w, 512, 0,
                                             pred_b, nullptr, out, 128, 512);
}